// Round 4
// baseline (1437.504 us; speedup 1.0000x reference)
//
#include <hip/hip_runtime.h>
#include <hip/hip_fp16.h>

#define USER_NUM 100000
#define ITEM_NUM 150000
#define N_NODES  250000
#define EMB      64
#define N_EDGES  1200000
#define N_ELEM   (N_NODES * EMB)   // 16,000,000

#define GRID   1024                // 4 blocks/CU x 256 CUs — exactly co-resident
#define NBLK_E 512                 // bin chunks
#define NBUCK  245                 // ceil(N_NODES/1024) buckets of 1024 rows
#define CAP    8192                // records per bucket region in tmp
#define TB1    4096                // bin tile buffer (max padded 2344+245*7=4059)
#define INIT_TILES 3907            // ceil(N_ELEM/16 / 256)
#define SPMM_TASKS 15625           // 250000 rows * 16 lanes / 256 threads (exact)

typedef float f4 __attribute__((ext_vector_type(4)));
typedef int   i4 __attribute__((ext_vector_type(4)));

union SMem {
    struct {
        int scnt[256];             // per-bucket count, later placement cursor
        int spref[256];            // padded exclusive prefix (246 used)
        int schunk[NBUCK];         // global chunk base per bucket
        unsigned char sbuck[TB1];  // slot -> bucket id
        int2 tilebuf[TB1];         // 32 KB
    } B;                           // ~39.9 KB total  (<= 40960 for 4 blocks/CU)
    struct {
        int shist[1024];
        int swave[256];
    } C;
};

// ---- device-wide barrier: monotonic counter, agent-scope atomics ----
__device__ __forceinline__ void gridbar(unsigned* bar) {
    __syncthreads();
    if (threadIdx.x == 0) {
        __threadfence();   // release prior writes device-wide
        unsigned old = __hip_atomic_fetch_add(bar, 1u, __ATOMIC_ACQ_REL,
                                              __HIP_MEMORY_SCOPE_AGENT);
        unsigned target = (old / GRID + 1u) * GRID;
        while (__hip_atomic_load(bar, __ATOMIC_ACQUIRE,
                                 __HIP_MEMORY_SCOPE_AGENT) < target)
            __builtin_amdgcn_s_sleep(8);
        __threadfence();   // acquire
    }
    __syncthreads();
}

// ---- phase B.a: bin one edge chunk into 1024-row bucket regions of tmp ----
__device__ void bin_task(SMem& sm, int b,
                         const int* __restrict__ rows, const int* __restrict__ cols,
                         const float* __restrict__ vals,
                         int* __restrict__ chunkcur, int* __restrict__ bucket_cnt,
                         int2* __restrict__ tmp)
{
    int t  = threadIdx.x;
    int e0 = (int)((long long)b * N_EDGES / NBLK_E);
    int e1 = (int)((long long)(b + 1) * N_EDGES / NBLK_E);

    sm.B.scnt[t] = 0;
    __syncthreads();
    for (int e = e0 + t; e < e1; e += 256)
        atomicAdd(&sm.B.scnt[rows[e] >> 10], 1);
    __syncthreads();
    int realc = (t < NBUCK) ? sm.B.scnt[t] : 0;
    int v     = (realc + 7) & ~7;            // pad to 8-record chunks
    __syncthreads();
    sm.B.spref[t] = v;
    __syncthreads();
    for (int off = 1; off < 256; off <<= 1) {
        int u = (t >= off) ? sm.B.spref[t - off] : 0;
        __syncthreads();
        sm.B.spref[t] += u;
        __syncthreads();
    }
    int excl = sm.B.spref[t] - v;
    __syncthreads();
    sm.B.spref[t] = excl;                     // exclusive; spref[245]=total
    __syncthreads();
    int padded_total = sm.B.spref[NBUCK];

    sm.B.scnt[t] = excl;                      // placement cursor
    if (t < NBUCK) {
        sm.B.schunk[t] = (v > 0) ? atomicAdd(&chunkcur[t], v >> 3) : 0;
        if (realc > 0) atomicAdd(&bucket_cnt[t], realc);
        for (int k = realc; k < v; ++k) sm.B.tilebuf[excl + k] = make_int2(-1, 0);
        for (int k = 0; k < v; ++k)     sm.B.sbuck[excl + k] = (unsigned char)t;
    }
    __syncthreads();
    for (int e = e0 + t; e < e1; e += 256) {
        int r  = rows[e];
        int lp = atomicAdd(&sm.B.scnt[r >> 10], 1);
        sm.B.tilebuf[lp] = make_int2(((r & 1023) << 18) | cols[e], __float_as_int(vals[e]));
    }
    __syncthreads();
    for (int j = t; j < padded_total; j += 256) {
        int lo = sm.B.sbuck[j];
        tmp[(size_t)lo * CAP + sm.B.schunk[lo] * 8 + (j - sm.B.spref[lo])] = sm.B.tilebuf[j];
    }
    __syncthreads();
}

// ---- phase B.b: fp32 user||item -> fp16 table, 16 elems/thread ----
__device__ void init_task(int tile,
                          const float* __restrict__ user, const float* __restrict__ item,
                          __half* __restrict__ emb16)
{
    int gi = tile * 256 + threadIdx.x;
    if (gi >= N_ELEM / 16) return;
    int base = gi * 16;
    const int UE = USER_NUM * EMB;   // 6.4M, 16-aligned
    const f4* src = (base < UE) ? (const f4*)(user + base)
                                : (const f4*)(item + (base - UE));
    f4 f0 = __builtin_nontemporal_load(src);
    f4 f1 = __builtin_nontemporal_load(src + 1);
    f4 f2 = __builtin_nontemporal_load(src + 2);
    f4 f3 = __builtin_nontemporal_load(src + 3);
    union { i4 v; __half2 h[4]; } a, b;
    a.h[0] = __float22half2_rn(make_float2(f0.x, f0.y));
    a.h[1] = __float22half2_rn(make_float2(f0.z, f0.w));
    a.h[2] = __float22half2_rn(make_float2(f1.x, f1.y));
    a.h[3] = __float22half2_rn(make_float2(f1.z, f1.w));
    b.h[0] = __float22half2_rn(make_float2(f2.x, f2.y));
    b.h[1] = __float22half2_rn(make_float2(f2.z, f2.w));
    b.h[2] = __float22half2_rn(make_float2(f3.x, f3.y));
    b.h[3] = __float22half2_rn(make_float2(f3.z, f3.w));
    ((i4*)(emb16 + base))[0] = a.v;
    ((i4*)(emb16 + base))[1] = b.v;
}

// ---- phase C: place one bucket into CSR (direct global scatter, single-XCD region) ----
__device__ void place_task(SMem& sm, int b,
                           const int* __restrict__ chunkcur, const int* __restrict__ bucket_cnt,
                           const int2* __restrict__ tmp,
                           int* __restrict__ row_ptr, int2* __restrict__ edges)
{
    int t = threadIdx.x;

    // scan of the 245 bucket totals -> this bucket's global base
    int vv = (t < NBUCK) ? bucket_cnt[t] : 0;
    sm.C.swave[t] = vv;
    __syncthreads();
    for (int off = 1; off < 256; off <<= 1) {
        int u = (t >= off) ? sm.C.swave[t - off] : 0;
        __syncthreads();
        sm.C.swave[t] += u;
        __syncthreads();
    }
    int bb = (b == 0) ? 0 : sm.C.swave[b - 1];

    for (int i = t; i < 1024; i += 256) sm.C.shist[i] = 0;
    __syncthreads();

    int nrec = chunkcur[b] * 8;
    const int2* src = tmp + (size_t)b * CAP;
    for (int j = t; j < nrec; j += 256) {
        int x = src[j].x;
        if (x != -1) atomicAdd(&sm.C.shist[x >> 18], 1);
    }
    __syncthreads();
    int h0 = sm.C.shist[4 * t], h1 = sm.C.shist[4 * t + 1];
    int h2 = sm.C.shist[4 * t + 2], h3 = sm.C.shist[4 * t + 3];
    int sum = h0 + h1 + h2 + h3;
    sm.C.swave[t] = sum;
    __syncthreads();
    for (int off = 1; off < 256; off <<= 1) {
        int u = (t >= off) ? sm.C.swave[t - off] : 0;
        __syncthreads();
        sm.C.swave[t] += u;
        __syncthreads();
    }
    int base = bb + sm.C.swave[t] - sum;      // absolute CSR offsets
    __syncthreads();
    sm.C.shist[4 * t]     = base;
    sm.C.shist[4 * t + 1] = base + h0;
    sm.C.shist[4 * t + 2] = base + h0 + h1;
    sm.C.shist[4 * t + 3] = base + h0 + h1 + h2;
    __syncthreads();
    for (int i = t; i < 1024; i += 256) {
        int idx = b * 1024 + i;
        if (idx < N_NODES) row_ptr[idx] = sm.C.shist[i];
    }
    if (b == 0 && t == 0) row_ptr[N_NODES] = N_EDGES;
    __syncthreads();
    // direct scatter: bucket region <= ~41KB, written only by this block -> no
    // cross-XCD partial-line write amplification
    for (int j = t; j < nrec; j += 256) {
        int2 rec = src[j];
        if (rec.x != -1) {
            int lp = atomicAdd(&sm.C.shist[rec.x >> 18], 1);
            edges[lp] = make_int2(rec.x & 0x3FFFF, rec.y);
        }
    }
    __syncthreads();
}

// ---- phases D/E/F: SpMM, quarter-wave (16 lanes) per row, ILP-8, grid-stride ----
template <int MODE>
__device__ void spmm_phase(const int* __restrict__ row_ptr, const int2* __restrict__ edges,
                           const __half* __restrict__ in16, const __half* __restrict__ emb16,
                           const __half* __restrict__ cur1,
                           float* __restrict__ out, __half* __restrict__ cur_out)
{
    int tl = threadIdx.x & 15;
    int tr = threadIdx.x >> 4;
    for (int task = blockIdx.x; task < SPMM_TASKS; task += GRID) {
        int r   = task * 16 + tr;             // r < 250000 always (15625*16 exact)
        int start = row_ptr[r];
        int end   = row_ptr[r + 1];
        int idx   = r * EMB + 4 * tl;

        union { int2 i; __half2 h[2]; } pe, p1, p2;
        if (MODE == 1) {
            pe.i = *(const int2*)(emb16 + idx);
            p1.i = *(const int2*)(cur1 + idx);
            p2.i = *(const int2*)(in16 + idx);
        }

        float ax = 0.f, ay = 0.f, az = 0.f, aw = 0.f;
        for (int j = start; j < end; j += 8) {
            int2 e[8];
#pragma unroll
            for (int k = 0; k < 8; ++k) e[k] = edges[j + k];   // pad-read past end ok
#pragma unroll
            for (int k = 0; k < 8; ++k) {
                bool ok = (j + k < end);
                int   c = ok ? e[k].x : 0;
                float v = ok ? __int_as_float(e[k].y) : 0.0f;
                union { int2 i; __half2 h[2]; } g;
                g.i = *(const int2*)(in16 + c * EMB + 4 * tl);
                float2 x0 = __half22float2(g.h[0]);
                float2 x1 = __half22float2(g.h[1]);
                ax += v * x0.x; ay += v * x0.y;
                az += v * x1.x; aw += v * x1.y;
            }
        }

        if (MODE == 0) {
            union { int2 i; __half2 h[2]; } o;
            o.h[0] = __float22half2_rn(make_float2(ax, ay));
            o.h[1] = __float22half2_rn(make_float2(az, aw));
            *(int2*)(cur_out + idx) = o.i;
        } else {
            float2 e0 = __half22float2(pe.h[0]), e1 = __half22float2(pe.h[1]);
            float2 c0 = __half22float2(p1.h[0]), c1 = __half22float2(p1.h[1]);
            float2 d0 = __half22float2(p2.h[0]), d1 = __half22float2(p2.h[1]);
            float4 o = make_float4(e0.x + c0.x + d0.x + ax,
                                   e0.y + c0.y + d0.y + ay,
                                   e1.x + c1.x + d1.x + az,
                                   e1.y + c1.y + d1.y + aw);
            *(float4*)(out + idx) = o;
        }
    }
}

// ---- the persistent mega-kernel: everything in one dispatch ----
__global__ __launch_bounds__(256, 4) void mega_kernel(
    const int* __restrict__ rows, const int* __restrict__ cols,
    const float* __restrict__ vals,
    const float* __restrict__ user, const float* __restrict__ item,
    __half* __restrict__ emb16, __half* __restrict__ cur1, __half* __restrict__ cur2,
    int2* __restrict__ tmp, int2* __restrict__ edges, int* __restrict__ row_ptr,
    int* __restrict__ bucket_cnt, int* __restrict__ chunkcur,
    unsigned* __restrict__ bar, float* __restrict__ out)
{
    __shared__ SMem sm;

    // phase B: bin edges (tasks 0..511) || fp16 table init (tasks 512..4418)
    for (int task = blockIdx.x; task < NBLK_E + INIT_TILES; task += GRID) {
        if (task < NBLK_E) bin_task(sm, task, rows, cols, vals, chunkcur, bucket_cnt, tmp);
        else               init_task(task - NBLK_E, user, item, emb16);
    }
    gridbar(bar);

    // phase C: place CSR (245 buckets)
    for (int b = blockIdx.x; b < NBUCK; b += GRID)
        place_task(sm, b, chunkcur, bucket_cnt, tmp, row_ptr, edges);
    gridbar(bar);

    // phases D/E/F: 3 spmm hops
    spmm_phase<0>(row_ptr, edges, emb16, emb16, cur1, out, cur1);
    gridbar(bar);
    spmm_phase<0>(row_ptr, edges, cur1, emb16, cur1, out, cur2);
    gridbar(bar);
    spmm_phase<1>(row_ptr, edges, cur2, emb16, cur1, out, nullptr);
}

extern "C" void kernel_launch(void* const* d_in, const int* in_sizes, int n_in,
                              void* d_out, int out_size, void* d_ws, size_t ws_size,
                              hipStream_t stream) {
    const int*   rows = (const int*)d_in[2];
    const int*   cols = (const int*)d_in[3];
    const float* vals = (const float*)d_in[4];
    const float* user = (const float*)d_in[0];
    const float* item = (const float*)d_in[1];
    float*       out  = (float*)d_out;

    // workspace layout (256B aligned), ~123 MB total
    char* p = (char*)d_ws;
    __half* emb16   = (__half*)p;  p += (size_t)N_ELEM * 2;             // 32 MB
    __half* cur1    = (__half*)p;  p += (size_t)N_ELEM * 2;             // 32 MB
    __half* cur2    = (__half*)p;  p += (size_t)N_ELEM * 2;             // 32 MB
    int2*   tmp     = (int2*)p;    p += (size_t)NBUCK * CAP * 8;        // 16.1 MB
    int2*   edges   = (int2*)p;    p += (size_t)(N_EDGES + 32) * 8;     // 9.6 MB + pad
    int*    row_ptr = (int*)p;     p += 1000448;                        // 250001*4 padded
    int*       bucket_cnt = (int*)p;      p += 1024;                    // zeroed
    int*       chunkcur   = (int*)p;      p += 1024;                    // zeroed
    unsigned*  bar        = (unsigned*)p; p += 2048;                    // zeroed

    // one small memset: bucket_cnt + chunkcur + barrier counter
    hipMemsetAsync(bucket_cnt, 0, 4096, stream);

    void* args[] = { (void*)&rows, (void*)&cols, (void*)&vals,
                     (void*)&user, (void*)&item,
                     (void*)&emb16, (void*)&cur1, (void*)&cur2,
                     (void*)&tmp, (void*)&edges, (void*)&row_ptr,
                     (void*)&bucket_cnt, (void*)&chunkcur,
                     (void*)&bar, (void*)&out };
    hipError_t err = hipLaunchCooperativeKernel(
        reinterpret_cast<const void*>(mega_kernel),
        dim3(GRID), dim3(256), args, 0, stream);
    if (err != hipSuccess) {
        // fallback: normal launch — grid == exact co-resident capacity
        // (1024 blocks = 256 CUs x 4 blocks/CU by __launch_bounds__(256,4) + 39.9KB LDS)
        mega_kernel<<<dim3(GRID), dim3(256), 0, stream>>>(
            rows, cols, vals, user, item, emb16, cur1, cur2,
            tmp, edges, row_ptr, bucket_cnt, chunkcur, bar, out);
    }
}

// Round 5
// 693.657 us; speedup vs baseline: 2.0724x; 2.0724x over previous
//
#include <hip/hip_runtime.h>
#include <hip/hip_fp16.h>

#define USER_NUM 100000
#define ITEM_NUM 150000
#define N_NODES  250000
#define EMB      64
#define N_EDGES  1200000
#define N_ELEM   (N_NODES * EMB)   // 16,000,000

#define GRID   1024                // 4 blocks/CU x 256 CUs — exactly co-resident
#define NBLK_E 512                 // bin chunks
#define NBUCK  245                 // ceil(N_NODES/1024) buckets of 1024 rows
#define CAP    8192                // records per bucket region in tmp
#define TB1    4096                // bin tile buffer (max padded 2344+245*7=4059)
#define INIT_TILES 3907            // ceil(N_ELEM/16 / 256)
#define SPMM_TASKS 15625           // 250000 rows * 16 lanes / 256 threads (exact)

typedef float f4 __attribute__((ext_vector_type(4)));
typedef int   i4 __attribute__((ext_vector_type(4)));

union SMem {
    struct {
        int scnt[256];             // per-bucket count, later placement cursor
        int spref[256];            // padded exclusive prefix (246 used)
        int schunk[NBUCK];         // global chunk base per bucket
        unsigned char sbuck[TB1];  // slot -> bucket id
        int2 tilebuf[TB1];         // 32 KB
    } B;                           // ~39.9 KB total  (<= 40960 for 4 blocks/CU)
    struct {
        int shist[1024];
        int swave[256];
    } C;
};

// ---- device-wide barrier, v2 ----
// Round-4 version polled with ACQUIRE agent loads: on gfx950 every such load
// emits a whole-cache buffer_inv (L1+L2), so spinning blocks continuously
// invalidated the XCD L2s of still-working blocks -> 5x latency blowup.
// v2: relaxed RMW + relaxed polls (per-address cache bypass only), exactly one
// release fence before arrival and one acquire fence after exit.
__device__ __forceinline__ void gridbar(unsigned* bar) {
    __syncthreads();
    if (threadIdx.x == 0) {
        __builtin_amdgcn_fence(__ATOMIC_RELEASE, "agent");   // one wbl2
        unsigned old = __hip_atomic_fetch_add(bar, 1u, __ATOMIC_RELAXED,
                                              __HIP_MEMORY_SCOPE_AGENT);
        unsigned target = (old / GRID + 1u) * GRID;
        while (__hip_atomic_load(bar, __ATOMIC_RELAXED,
                                 __HIP_MEMORY_SCOPE_AGENT) < target)
            __builtin_amdgcn_s_sleep(16);
        __builtin_amdgcn_fence(__ATOMIC_ACQUIRE, "agent");   // one inv
    }
    __syncthreads();
}

// ---- phase B.a: bin one edge chunk into 1024-row bucket regions of tmp ----
__device__ void bin_task(SMem& sm, int b,
                         const int* __restrict__ rows, const int* __restrict__ cols,
                         const float* __restrict__ vals,
                         int* __restrict__ chunkcur, int* __restrict__ bucket_cnt,
                         int2* __restrict__ tmp)
{
    int t  = threadIdx.x;
    int e0 = (int)((long long)b * N_EDGES / NBLK_E);
    int e1 = (int)((long long)(b + 1) * N_EDGES / NBLK_E);

    sm.B.scnt[t] = 0;
    __syncthreads();
    for (int e = e0 + t; e < e1; e += 256)
        atomicAdd(&sm.B.scnt[rows[e] >> 10], 1);
    __syncthreads();
    int realc = (t < NBUCK) ? sm.B.scnt[t] : 0;
    int v     = (realc + 7) & ~7;            // pad to 8-record chunks
    __syncthreads();
    sm.B.spref[t] = v;
    __syncthreads();
    for (int off = 1; off < 256; off <<= 1) {
        int u = (t >= off) ? sm.B.spref[t - off] : 0;
        __syncthreads();
        sm.B.spref[t] += u;
        __syncthreads();
    }
    int excl = sm.B.spref[t] - v;
    __syncthreads();
    sm.B.spref[t] = excl;                     // exclusive; spref[245]=total
    __syncthreads();
    int padded_total = sm.B.spref[NBUCK];

    sm.B.scnt[t] = excl;                      // placement cursor
    if (t < NBUCK) {
        sm.B.schunk[t] = (v > 0) ? atomicAdd(&chunkcur[t], v >> 3) : 0;
        if (realc > 0) atomicAdd(&bucket_cnt[t], realc);
        for (int k = realc; k < v; ++k) sm.B.tilebuf[excl + k] = make_int2(-1, 0);
        for (int k = 0; k < v; ++k)     sm.B.sbuck[excl + k] = (unsigned char)t;
    }
    __syncthreads();
    for (int e = e0 + t; e < e1; e += 256) {
        int r  = rows[e];
        int lp = atomicAdd(&sm.B.scnt[r >> 10], 1);
        sm.B.tilebuf[lp] = make_int2(((r & 1023) << 18) | cols[e], __float_as_int(vals[e]));
    }
    __syncthreads();
    for (int j = t; j < padded_total; j += 256) {
        int lo = sm.B.sbuck[j];
        tmp[(size_t)lo * CAP + sm.B.schunk[lo] * 8 + (j - sm.B.spref[lo])] = sm.B.tilebuf[j];
    }
    __syncthreads();
}

// ---- phase B.b: fp32 user||item -> fp16 table, 16 elems/thread ----
__device__ void init_task(int tile,
                          const float* __restrict__ user, const float* __restrict__ item,
                          __half* __restrict__ emb16)
{
    int gi = tile * 256 + threadIdx.x;
    if (gi >= N_ELEM / 16) return;
    int base = gi * 16;
    const int UE = USER_NUM * EMB;   // 6.4M, 16-aligned
    const f4* src = (base < UE) ? (const f4*)(user + base)
                                : (const f4*)(item + (base - UE));
    f4 f0 = __builtin_nontemporal_load(src);
    f4 f1 = __builtin_nontemporal_load(src + 1);
    f4 f2 = __builtin_nontemporal_load(src + 2);
    f4 f3 = __builtin_nontemporal_load(src + 3);
    union { i4 v; __half2 h[4]; } a, b;
    a.h[0] = __float22half2_rn(make_float2(f0.x, f0.y));
    a.h[1] = __float22half2_rn(make_float2(f0.z, f0.w));
    a.h[2] = __float22half2_rn(make_float2(f1.x, f1.y));
    a.h[3] = __float22half2_rn(make_float2(f1.z, f1.w));
    b.h[0] = __float22half2_rn(make_float2(f2.x, f2.y));
    b.h[1] = __float22half2_rn(make_float2(f2.z, f2.w));
    b.h[2] = __float22half2_rn(make_float2(f3.x, f3.y));
    b.h[3] = __float22half2_rn(make_float2(f3.z, f3.w));
    ((i4*)(emb16 + base))[0] = a.v;
    ((i4*)(emb16 + base))[1] = b.v;
}

// ---- phase C: place one bucket into CSR (direct global scatter, single-XCD region) ----
__device__ void place_task(SMem& sm, int b,
                           const int* __restrict__ chunkcur, const int* __restrict__ bucket_cnt,
                           const int2* __restrict__ tmp,
                           int* __restrict__ row_ptr, int2* __restrict__ edges)
{
    int t = threadIdx.x;

    // scan of the 245 bucket totals -> this bucket's global base
    int vv = (t < NBUCK) ? bucket_cnt[t] : 0;
    sm.C.swave[t] = vv;
    __syncthreads();
    for (int off = 1; off < 256; off <<= 1) {
        int u = (t >= off) ? sm.C.swave[t - off] : 0;
        __syncthreads();
        sm.C.swave[t] += u;
        __syncthreads();
    }
    int bb = (b == 0) ? 0 : sm.C.swave[b - 1];

    for (int i = t; i < 1024; i += 256) sm.C.shist[i] = 0;
    __syncthreads();

    int nrec = chunkcur[b] * 8;
    const int2* src = tmp + (size_t)b * CAP;
    for (int j = t; j < nrec; j += 256) {
        int x = src[j].x;
        if (x != -1) atomicAdd(&sm.C.shist[x >> 18], 1);
    }
    __syncthreads();
    int h0 = sm.C.shist[4 * t], h1 = sm.C.shist[4 * t + 1];
    int h2 = sm.C.shist[4 * t + 2], h3 = sm.C.shist[4 * t + 3];
    int sum = h0 + h1 + h2 + h3;
    sm.C.swave[t] = sum;
    __syncthreads();
    for (int off = 1; off < 256; off <<= 1) {
        int u = (t >= off) ? sm.C.swave[t - off] : 0;
        __syncthreads();
        sm.C.swave[t] += u;
        __syncthreads();
    }
    int base = bb + sm.C.swave[t] - sum;      // absolute CSR offsets
    __syncthreads();
    sm.C.shist[4 * t]     = base;
    sm.C.shist[4 * t + 1] = base + h0;
    sm.C.shist[4 * t + 2] = base + h0 + h1;
    sm.C.shist[4 * t + 3] = base + h0 + h1 + h2;
    __syncthreads();
    for (int i = t; i < 1024; i += 256) {
        int idx = b * 1024 + i;
        if (idx < N_NODES) row_ptr[idx] = sm.C.shist[i];
    }
    if (b == 0 && t == 0) row_ptr[N_NODES] = N_EDGES;
    __syncthreads();
    // direct scatter: bucket region <= ~41KB, written only by this block -> no
    // cross-XCD partial-line write amplification
    for (int j = t; j < nrec; j += 256) {
        int2 rec = src[j];
        if (rec.x != -1) {
            int lp = atomicAdd(&sm.C.shist[rec.x >> 18], 1);
            edges[lp] = make_int2(rec.x & 0x3FFFF, rec.y);
        }
    }
    __syncthreads();
}

// ---- phases D/E/F: SpMM, quarter-wave (16 lanes) per row, ILP-8, grid-stride ----
template <int MODE>
__device__ void spmm_phase(const int* __restrict__ row_ptr, const int2* __restrict__ edges,
                           const __half* __restrict__ in16, const __half* __restrict__ emb16,
                           const __half* __restrict__ cur1,
                           float* __restrict__ out, __half* __restrict__ cur_out)
{
    int tl = threadIdx.x & 15;
    int tr = threadIdx.x >> 4;
    for (int task = blockIdx.x; task < SPMM_TASKS; task += GRID) {
        int r   = task * 16 + tr;             // r < 250000 always (15625*16 exact)
        int start = row_ptr[r];
        int end   = row_ptr[r + 1];
        int idx   = r * EMB + 4 * tl;

        union { int2 i; __half2 h[2]; } pe, p1, p2;
        if (MODE == 1) {
            pe.i = *(const int2*)(emb16 + idx);
            p1.i = *(const int2*)(cur1 + idx);
            p2.i = *(const int2*)(in16 + idx);
        }

        float ax = 0.f, ay = 0.f, az = 0.f, aw = 0.f;
        for (int j = start; j < end; j += 8) {
            int2 e[8];
#pragma unroll
            for (int k = 0; k < 8; ++k) e[k] = edges[j + k];   // pad-read past end ok
#pragma unroll
            for (int k = 0; k < 8; ++k) {
                bool ok = (j + k < end);
                int   c = ok ? e[k].x : 0;
                float v = ok ? __int_as_float(e[k].y) : 0.0f;
                union { int2 i; __half2 h[2]; } g;
                g.i = *(const int2*)(in16 + c * EMB + 4 * tl);
                float2 x0 = __half22float2(g.h[0]);
                float2 x1 = __half22float2(g.h[1]);
                ax += v * x0.x; ay += v * x0.y;
                az += v * x1.x; aw += v * x1.y;
            }
        }

        if (MODE == 0) {
            union { int2 i; __half2 h[2]; } o;
            o.h[0] = __float22half2_rn(make_float2(ax, ay));
            o.h[1] = __float22half2_rn(make_float2(az, aw));
            *(int2*)(cur_out + idx) = o.i;
        } else {
            float2 e0 = __half22float2(pe.h[0]), e1 = __half22float2(pe.h[1]);
            float2 c0 = __half22float2(p1.h[0]), c1 = __half22float2(p1.h[1]);
            float2 d0 = __half22float2(p2.h[0]), d1 = __half22float2(p2.h[1]);
            float4 o = make_float4(e0.x + c0.x + d0.x + ax,
                                   e0.y + c0.y + d0.y + ay,
                                   e1.x + c1.x + d1.x + az,
                                   e1.y + c1.y + d1.y + aw);
            *(float4*)(out + idx) = o;
        }
    }
}

// ---- the persistent mega-kernel: everything in one dispatch ----
__global__ __launch_bounds__(256, 4) void mega_kernel(
    const int* __restrict__ rows, const int* __restrict__ cols,
    const float* __restrict__ vals,
    const float* __restrict__ user, const float* __restrict__ item,
    __half* __restrict__ emb16, __half* __restrict__ cur1, __half* __restrict__ cur2,
    int2* __restrict__ tmp, int2* __restrict__ edges, int* __restrict__ row_ptr,
    int* __restrict__ bucket_cnt, int* __restrict__ chunkcur,
    unsigned* __restrict__ bar, float* __restrict__ out)
{
    __shared__ SMem sm;

    // phase B: bin edges (tasks 0..511) || fp16 table init (tasks 512..4418)
    for (int task = blockIdx.x; task < NBLK_E + INIT_TILES; task += GRID) {
        if (task < NBLK_E) bin_task(sm, task, rows, cols, vals, chunkcur, bucket_cnt, tmp);
        else               init_task(task - NBLK_E, user, item, emb16);
    }
    gridbar(bar);

    // phase C: place CSR (245 buckets)
    for (int b = blockIdx.x; b < NBUCK; b += GRID)
        place_task(sm, b, chunkcur, bucket_cnt, tmp, row_ptr, edges);
    gridbar(bar);

    // phases D/E/F: 3 spmm hops
    spmm_phase<0>(row_ptr, edges, emb16, emb16, cur1, out, cur1);
    gridbar(bar);
    spmm_phase<0>(row_ptr, edges, cur1, emb16, cur1, out, cur2);
    gridbar(bar);
    spmm_phase<1>(row_ptr, edges, cur2, emb16, cur1, out, nullptr);
}

extern "C" void kernel_launch(void* const* d_in, const int* in_sizes, int n_in,
                              void* d_out, int out_size, void* d_ws, size_t ws_size,
                              hipStream_t stream) {
    const int*   rows = (const int*)d_in[2];
    const int*   cols = (const int*)d_in[3];
    const float* vals = (const float*)d_in[4];
    const float* user = (const float*)d_in[0];
    const float* item = (const float*)d_in[1];
    float*       out  = (float*)d_out;

    // workspace layout (256B aligned), ~123 MB total
    char* p = (char*)d_ws;
    __half* emb16   = (__half*)p;  p += (size_t)N_ELEM * 2;             // 32 MB
    __half* cur1    = (__half*)p;  p += (size_t)N_ELEM * 2;             // 32 MB
    __half* cur2    = (__half*)p;  p += (size_t)N_ELEM * 2;             // 32 MB
    int2*   tmp     = (int2*)p;    p += (size_t)NBUCK * CAP * 8;        // 16.1 MB
    int2*   edges   = (int2*)p;    p += (size_t)(N_EDGES + 32) * 8;     // 9.6 MB + pad
    int*    row_ptr = (int*)p;     p += 1000448;                        // 250001*4 padded
    int*       bucket_cnt = (int*)p;      p += 1024;                    // zeroed
    int*       chunkcur   = (int*)p;      p += 1024;                    // zeroed
    unsigned*  bar        = (unsigned*)p; p += 2048;                    // zeroed

    // one small memset: bucket_cnt + chunkcur + barrier counter
    hipMemsetAsync(bucket_cnt, 0, 4096, stream);

    void* args[] = { (void*)&rows, (void*)&cols, (void*)&vals,
                     (void*)&user, (void*)&item,
                     (void*)&emb16, (void*)&cur1, (void*)&cur2,
                     (void*)&tmp, (void*)&edges, (void*)&row_ptr,
                     (void*)&bucket_cnt, (void*)&chunkcur,
                     (void*)&bar, (void*)&out };
    hipError_t err = hipLaunchCooperativeKernel(
        reinterpret_cast<const void*>(mega_kernel),
        dim3(GRID), dim3(256), args, 0, stream);
    if (err != hipSuccess) {
        // fallback: normal launch — grid == exact co-resident capacity
        // (1024 blocks = 256 CUs x 4 blocks/CU by __launch_bounds__(256,4) + 39.9KB LDS)
        mega_kernel<<<dim3(GRID), dim3(256), 0, stream>>>(
            rows, cols, vals, user, item, emb16, cur1, cur2,
            tmp, edges, row_ptr, bucket_cnt, chunkcur, bar, out);
    }
}

// Round 6
// 287.692 us; speedup vs baseline: 4.9967x; 2.4111x over previous
//
#include <hip/hip_runtime.h>
#include <hip/hip_fp16.h>

#define USER_NUM 100000
#define ITEM_NUM 150000
#define N_NODES  250000
#define EMB      64
#define N_EDGES  1200000
#define N_ELEM   (N_NODES * EMB)   // 16,000,000

#define NBLK_E 512                 // bin chunks (2344 edges each)
#define NBUCK  245                 // ceil(N_NODES/1024) buckets of 1024 rows
#define CAP    8192                // record capacity per bucket region in tmp (max ~5200 used)
#define INIT_TILES 3907            // ceil(N_ELEM/16 / 256)

typedef float f4 __attribute__((ext_vector_type(4)));
typedef int   i4 __attribute__((ext_vector_type(4)));

// ------- phase 1 (fused): blocks [0,NBLK_E) bin edges; rest fp16 table init -------
// Lean bin: dense per-(block,bucket) chunks in tmp (record-exact cursors, no padding,
// no tilebuf staging, no flush scan). 2 KB LDS -> full occupancy. Each block's chunk
// regions are block-exclusive => lines fully dirtied within one XCD's L2 (no round-3
// cross-XCD partial-line write amplification).
__global__ __launch_bounds__(256) void bin_init_kernel(
    const int* __restrict__ rows, const int* __restrict__ cols,
    const float* __restrict__ vals,
    int* __restrict__ chunkcur, int2* __restrict__ tmp,
    const float* __restrict__ user, const float* __restrict__ item,
    __half* __restrict__ emb16)
{
    int t = threadIdx.x;

    if (blockIdx.x >= NBLK_E) {
        // ---- init path: 16 elems/thread, fp32 user||item -> fp16 table ----
        int gi = (blockIdx.x - NBLK_E) * 256 + t;
        if (gi < N_ELEM / 16) {
            int base = gi * 16;
            const int UE = USER_NUM * EMB;   // 6.4M, 16-aligned
            const f4* src = (base < UE) ? (const f4*)(user + base)
                                        : (const f4*)(item + (base - UE));
            f4 f0 = __builtin_nontemporal_load(src);
            f4 f1 = __builtin_nontemporal_load(src + 1);
            f4 f2 = __builtin_nontemporal_load(src + 2);
            f4 f3 = __builtin_nontemporal_load(src + 3);
            union { i4 v; __half2 h[4]; } a, b;
            a.h[0] = __float22half2_rn(make_float2(f0.x, f0.y));
            a.h[1] = __float22half2_rn(make_float2(f0.z, f0.w));
            a.h[2] = __float22half2_rn(make_float2(f1.x, f1.y));
            a.h[3] = __float22half2_rn(make_float2(f1.z, f1.w));
            b.h[0] = __float22half2_rn(make_float2(f2.x, f2.y));
            b.h[1] = __float22half2_rn(make_float2(f2.z, f2.w));
            b.h[2] = __float22half2_rn(make_float2(f3.x, f3.y));
            b.h[3] = __float22half2_rn(make_float2(f3.z, f3.w));
            ((i4*)(emb16 + base))[0] = a.v;
            ((i4*)(emb16 + base))[1] = b.v;
        }
        return;
    }

    // ---- bin path ----
    __shared__ int scnt[256];    // hist, then per-bucket local cursor
    __shared__ int sbase[256];   // per-bucket global chunk base (records)

    int b  = blockIdx.x;
    int e0 = (int)((long long)b * N_EDGES / NBLK_E);
    int e1 = (int)((long long)(b + 1) * N_EDGES / NBLK_E);

    scnt[t] = 0;
    __syncthreads();
    for (int e = e0 + t; e < e1; e += 256)
        atomicAdd(&scnt[rows[e] >> 10], 1);
    __syncthreads();
    int realc = (t < NBUCK) ? scnt[t] : 0;
    if (t < NBUCK)
        sbase[t] = (realc > 0) ? atomicAdd(&chunkcur[t], realc) : 0;
    scnt[t] = 0;                 // local cursor (own index only; barrier below)
    __syncthreads();
    for (int e = e0 + t; e < e1; e += 256) {
        int r  = rows[e];
        int bk = r >> 10;
        int lp = atomicAdd(&scnt[bk], 1);
        tmp[(size_t)bk * CAP + sbase[bk] + lp] =
            make_int2(((r & 1023) << 18) | cols[e], __float_as_int(vals[e]));
    }
}

// ------- phase 2: place CSR. 980 blocks = (bucket, 256-row quarter) -------
// Each block: LDS scan of 245 bucket totals (redundant), full-bucket 1024-row
// histogram (4 KB), absolute CSR bases, row_ptr slice write, then direct global
// scatter of its 256-row window (~10 KB block-exclusive region, no staging).
__global__ __launch_bounds__(256) void place_kernel(
    const int* __restrict__ chunkcur, const int2* __restrict__ tmp,
    int* __restrict__ row_ptr, int2* __restrict__ edges)
{
    __shared__ int shist[1024];
    __shared__ int swave[256];

    int t = threadIdx.x;
    int b = blockIdx.x >> 2;     // bucket
    int s = blockIdx.x & 3;      // 256-row quarter

    // inclusive scan of the 245 bucket totals -> bucket base + count
    int vv = (t < NBUCK) ? chunkcur[t] : 0;
    swave[t] = vv;
    __syncthreads();
    for (int off = 1; off < 256; off <<= 1) {
        int u = (t >= off) ? swave[t - off] : 0;
        __syncthreads();
        swave[t] += u;
        __syncthreads();
    }
    int bb   = (b == 0) ? 0 : swave[b - 1];
    int nrec = swave[b] - bb;

    for (int i = t; i < 1024; i += 256) shist[i] = 0;
    __syncthreads();

    const int2* src = tmp + (size_t)b * CAP;
    for (int j = t; j < nrec; j += 256)
        atomicAdd(&shist[src[j].x >> 18], 1);
    __syncthreads();

    int h0 = shist[4 * t], h1 = shist[4 * t + 1];
    int h2 = shist[4 * t + 2], h3 = shist[4 * t + 3];
    int sum = h0 + h1 + h2 + h3;
    swave[t] = sum;
    __syncthreads();
    for (int off = 1; off < 256; off <<= 1) {
        int u = (t >= off) ? swave[t - off] : 0;
        __syncthreads();
        swave[t] += u;
        __syncthreads();
    }
    int base = bb + swave[t] - sum;          // absolute CSR offsets
    __syncthreads();
    shist[4 * t]     = base;
    shist[4 * t + 1] = base + h0;
    shist[4 * t + 2] = base + h0 + h1;
    shist[4 * t + 3] = base + h0 + h1 + h2;
    __syncthreads();

    // row_ptr slice for my 256-row window
    {
        int i   = s * 256 + t;               // local row
        int idx = b * 1024 + i;
        if (idx < N_NODES) row_ptr[idx] = shist[i];
    }
    if (blockIdx.x == 0 && t == 0) row_ptr[N_NODES] = N_EDGES;
    __syncthreads();

    // scatter my window directly to edges (block-exclusive ~10 KB region)
    for (int j = t; j < nrec; j += 256) {
        int2 rec = src[j];
        int  rl  = rec.x >> 18;
        if ((rl >> 8) == s) {
            int slot = atomicAdd(&shist[rl], 1);
            edges[slot] = make_int2(rec.x & 0x3FFFF, rec.y);
        }
    }
}

// ---------------- fused SpMM: quarter-wave (16 lanes) per row, ILP-8 ----------------
// Lane l owns dims [4l, 4l+4). MODE 0: cur_out = acc (fp16).
// MODE 1 (last layer): out = emb16[r] + cur1[r] + in16[r] + acc (fp32 store).
template <int MODE>
__global__ __launch_bounds__(256) void spmm_kernel(
    const int* __restrict__ row_ptr, const int2* __restrict__ edges,
    const __half* __restrict__ in16, const __half* __restrict__ emb16,
    const __half* __restrict__ cur1,
    float* __restrict__ out, __half* __restrict__ cur_out)
{
    int t = blockIdx.x * blockDim.x + threadIdx.x;
    int r = t >> 4;
    int l = t & 15;
    if (r >= N_NODES) return;
    int start = row_ptr[r];
    int end   = row_ptr[r + 1];
    int idx   = r * EMB + 4 * l;

    // prefetch epilogue terms (latency hides under the gather loop)
    union { int2 i; __half2 h[2]; } pe, p1, p2;
    if (MODE == 1) {
        pe.i = *(const int2*)(emb16 + idx);
        p1.i = *(const int2*)(cur1 + idx);
        p2.i = *(const int2*)(in16 + idx);
    }

    float ax = 0.f, ay = 0.f, az = 0.f, aw = 0.f;
    for (int j = start; j < end; j += 8) {
        int2 e[8];
#pragma unroll
        for (int k = 0; k < 8; ++k) e[k] = edges[j + k];   // pad-read past end ok
#pragma unroll
        for (int k = 0; k < 8; ++k) {
            bool ok = (j + k < end);
            int   c = ok ? e[k].x : 0;
            float v = ok ? __int_as_float(e[k].y) : 0.0f;
            union { int2 i; __half2 h[2]; } g;
            g.i = *(const int2*)(in16 + c * EMB + 4 * l);
            float2 x0 = __half22float2(g.h[0]);
            float2 x1 = __half22float2(g.h[1]);
            ax += v * x0.x; ay += v * x0.y;
            az += v * x1.x; aw += v * x1.y;
        }
    }

    if (MODE == 0) {
        union { int2 i; __half2 h[2]; } o;
        o.h[0] = __float22half2_rn(make_float2(ax, ay));
        o.h[1] = __float22half2_rn(make_float2(az, aw));
        *(int2*)(cur_out + idx) = o.i;
    } else {
        float2 e0 = __half22float2(pe.h[0]), e1 = __half22float2(pe.h[1]);
        float2 c0 = __half22float2(p1.h[0]), c1 = __half22float2(p1.h[1]);
        float2 d0 = __half22float2(p2.h[0]), d1 = __half22float2(p2.h[1]);
        float4 o = make_float4(e0.x + c0.x + d0.x + ax,
                               e0.y + c0.y + d0.y + ay,
                               e1.x + c1.x + d1.x + az,
                               e1.y + c1.y + d1.y + aw);
        *(float4*)(out + idx) = o;
    }
}

extern "C" void kernel_launch(void* const* d_in, const int* in_sizes, int n_in,
                              void* d_out, int out_size, void* d_ws, size_t ws_size,
                              hipStream_t stream) {
    const float* user = (const float*)d_in[0];
    const float* item = (const float*)d_in[1];
    const int*   rows = (const int*)d_in[2];
    const int*   cols = (const int*)d_in[3];
    const float* vals = (const float*)d_in[4];
    float*       out  = (float*)d_out;

    // workspace layout (256B aligned), ~123 MB total
    char* p = (char*)d_ws;
    __half* emb16   = (__half*)p;  p += (size_t)N_ELEM * 2;             // 32 MB
    __half* cur1    = (__half*)p;  p += (size_t)N_ELEM * 2;             // 32 MB
    __half* cur2    = (__half*)p;  p += (size_t)N_ELEM * 2;             // 32 MB
    int2*   tmp     = (int2*)p;    p += (size_t)NBUCK * CAP * 8;        // 16.1 MB
    int2*   edges   = (int2*)p;    p += (size_t)(N_EDGES + 32) * 8;     // 9.6 MB + pad
    int*    row_ptr = (int*)p;     p += 1000448;                        // 250001*4 padded
    int*    chunkcur = (int*)p;    p += 1024;                           // memset

    hipMemsetAsync(chunkcur, 0, 1024, stream);

    bin_init_kernel<<<NBLK_E + INIT_TILES, 256, 0, stream>>>(
        rows, cols, vals, chunkcur, tmp, user, item, emb16);
    place_kernel<<<NBUCK * 4, 256, 0, stream>>>(chunkcur, tmp, row_ptr, edges);

    const int spmm_blocks = (N_NODES * 16 + 255) / 256;   // 15625
    spmm_kernel<0><<<spmm_blocks, 256, 0, stream>>>(row_ptr, edges, emb16, emb16, cur1, out, cur1);
    spmm_kernel<0><<<spmm_blocks, 256, 0, stream>>>(row_ptr, edges, cur1, emb16, cur1, out, cur2);
    spmm_kernel<1><<<spmm_blocks, 256, 0, stream>>>(row_ptr, edges, cur2, emb16, cur1, out, nullptr);
}

// Round 7
// 286.740 us; speedup vs baseline: 5.0133x; 1.0033x over previous
//
#include <hip/hip_runtime.h>
#include <hip/hip_fp16.h>

#define USER_NUM 100000
#define ITEM_NUM 150000
#define N_NODES  250000
#define EMB      64
#define N_EDGES  1200000
#define N_ELEM   (N_NODES * EMB)   // 16,000,000

#define NBLK1 512                  // bin chunks (2344 edges each)
#define NBUCK 245                  // ceil(N_NODES/1024) buckets of 1024 rows
#define CAP   8192                 // records per bucket region in tmp
#define TB1   4096                 // bin tile buffer (max padded 2344+245*7=4059)
#define INIT_TILES 3907            // ceil(N_ELEM/16 / 256)
#define SST   2048                 // place window stage (max window ~1500 records)

typedef float f4 __attribute__((ext_vector_type(4)));
typedef int   i4 __attribute__((ext_vector_type(4)));

// ------- phase 1 (fused): blocks [0,NBLK1) bin edges; rest fp16 table init -------
// Round-2 proven bin: LDS tilebuf ordered by bucket, then COALESCED flush to tmp
// (scattered 8B global stores are the expensive primitive on this chip —
// rounds 3/6 showed 53-89us for scatter variants vs <=45us staged).
__global__ __launch_bounds__(256) void bin_init_kernel(
    const int* __restrict__ rows, const int* __restrict__ cols,
    const float* __restrict__ vals,
    int* __restrict__ chunkcur, int* __restrict__ bucket_cnt,
    int2* __restrict__ tmp,
    const float* __restrict__ user, const float* __restrict__ item,
    __half* __restrict__ emb16)
{
    __shared__ int  scnt[256];            // per-bucket count, later placement cursor
    __shared__ int  spref[256];           // padded exclusive prefix (246 used)
    __shared__ int  schunk[NBUCK];        // global chunk base per bucket
    __shared__ unsigned char sbuck[TB1];  // slot -> bucket id
    __shared__ int2 tilebuf[TB1];

    int t = threadIdx.x;

    if (blockIdx.x >= NBLK1) {
        // ---- init path: 16 elems/thread, fp32 user||item -> fp16 table ----
        int gi = (blockIdx.x - NBLK1) * 256 + t;
        if (gi < N_ELEM / 16) {
            int base = gi * 16;
            const int UE = USER_NUM * EMB;   // 6.4M, 16-aligned
            const f4* src = (base < UE) ? (const f4*)(user + base)
                                        : (const f4*)(item + (base - UE));
            f4 f0 = __builtin_nontemporal_load(src);
            f4 f1 = __builtin_nontemporal_load(src + 1);
            f4 f2 = __builtin_nontemporal_load(src + 2);
            f4 f3 = __builtin_nontemporal_load(src + 3);
            union { i4 v; __half2 h[4]; } a, b;
            a.h[0] = __float22half2_rn(make_float2(f0.x, f0.y));
            a.h[1] = __float22half2_rn(make_float2(f0.z, f0.w));
            a.h[2] = __float22half2_rn(make_float2(f1.x, f1.y));
            a.h[3] = __float22half2_rn(make_float2(f1.z, f1.w));
            b.h[0] = __float22half2_rn(make_float2(f2.x, f2.y));
            b.h[1] = __float22half2_rn(make_float2(f2.z, f2.w));
            b.h[2] = __float22half2_rn(make_float2(f3.x, f3.y));
            b.h[3] = __float22half2_rn(make_float2(f3.z, f3.w));
            ((i4*)(emb16 + base))[0] = a.v;
            ((i4*)(emb16 + base))[1] = b.v;
        }
        return;
    }

    // ---- bin path ----
    int b = blockIdx.x;
    int e0 = (int)((long long)b * N_EDGES / NBLK1);
    int e1 = (int)((long long)(b + 1) * N_EDGES / NBLK1);

    scnt[t] = 0;
    __syncthreads();
    for (int e = e0 + t; e < e1; e += 256)
        atomicAdd(&scnt[rows[e] >> 10], 1);
    __syncthreads();
    int realc = (t < NBUCK) ? scnt[t] : 0;
    int v     = (realc + 7) & ~7;            // pad to 8-record chunks
    __syncthreads();
    spref[t] = v;
    __syncthreads();
    for (int off = 1; off < 256; off <<= 1) {
        int u = (t >= off) ? spref[t - off] : 0;
        __syncthreads();
        spref[t] += u;
        __syncthreads();
    }
    int excl = spref[t] - v;
    __syncthreads();
    spref[t] = excl;                          // exclusive; spref[245]=total
    __syncthreads();
    int padded_total = spref[NBUCK];

    scnt[t] = excl;                           // placement cursor
    if (t < NBUCK) {
        schunk[t] = (v > 0) ? atomicAdd(&chunkcur[t], v >> 3) : 0;
        if (realc > 0) atomicAdd(&bucket_cnt[t], realc);
        for (int k = realc; k < v; ++k) tilebuf[excl + k] = make_int2(-1, 0);
        for (int k = 0; k < v; ++k)     sbuck[excl + k] = (unsigned char)t;
    }
    __syncthreads();
    for (int e = e0 + t; e < e1; e += 256) {
        int r  = rows[e];
        int lp = atomicAdd(&scnt[r >> 10], 1);
        tilebuf[lp] = make_int2(((r & 1023) << 18) | cols[e], __float_as_int(vals[e]));
    }
    __syncthreads();
    // flush: bucket-ordered -> coalesced runs into 64B-aligned chunk regions
    for (int j = t; j < padded_total; j += 256) {
        int lo = sbuck[j];
        tmp[(size_t)lo * CAP + schunk[lo] * 8 + (j - spref[lo])] = tilebuf[j];
    }
}

// ------- phase 2: place CSR. 980 blocks = (bucket, 256-row window) -------
// Pass A: full-bucket histogram (1024 rows). Scan -> absolute CSR bases.
// Write row_ptr slice. Pass B: stage THIS window's records into LDS (scatter
// hits LDS, cheap), then coalesced flush to the window's contiguous edges region.
__global__ __launch_bounds__(256) void place4_kernel(
    const int* __restrict__ chunkcur, const int* __restrict__ bucket_cnt,
    const int2* __restrict__ tmp,
    int* __restrict__ row_ptr, int2* __restrict__ edges)
{
    __shared__ int  shist[1024];
    __shared__ int  swave[256];
    __shared__ int2 sstage[SST];   // 16 KB

    int t = threadIdx.x;
    int b = blockIdx.x >> 2;       // bucket
    int s = blockIdx.x & 3;        // 256-row window

    // inclusive scan of 245 bucket totals -> bucket base bb, real count cnt
    int vv = (t < NBUCK) ? bucket_cnt[t] : 0;
    swave[t] = vv;
    __syncthreads();
    for (int off = 1; off < 256; off <<= 1) {
        int u = (t >= off) ? swave[t - off] : 0;
        __syncthreads();
        swave[t] += u;
        __syncthreads();
    }
    int bb  = (b == 0) ? 0 : swave[b - 1];
    int cnt = swave[b] - bb;
    __syncthreads();

    for (int i = t; i < 1024; i += 256) shist[i] = 0;
    __syncthreads();

    // pass A: histogram all 1024 rows of the bucket
    int nrec = chunkcur[b] * 8;
    const int2* src = tmp + (size_t)b * CAP;
    for (int j = t; j < nrec; j += 256) {
        int x = src[j].x;
        if (x != -1) atomicAdd(&shist[x >> 18], 1);
    }
    __syncthreads();

    // scan 1024 counts -> absolute bases
    int h0 = shist[4 * t], h1 = shist[4 * t + 1];
    int h2 = shist[4 * t + 2], h3 = shist[4 * t + 3];
    int sum = h0 + h1 + h2 + h3;
    swave[t] = sum;
    __syncthreads();
    for (int off = 1; off < 256; off <<= 1) {
        int u = (t >= off) ? swave[t - off] : 0;
        __syncthreads();
        swave[t] += u;
        __syncthreads();
    }
    int base = bb + swave[t] - sum;
    __syncthreads();
    shist[4 * t]     = base;
    shist[4 * t + 1] = base + h0;
    shist[4 * t + 2] = base + h0 + h1;
    shist[4 * t + 3] = base + h0 + h1 + h2;
    __syncthreads();

    // window bounds in edges[] + row_ptr slice
    int wstart = shist[s * 256];
    int wend   = (s < 3) ? shist[(s + 1) * 256] : bb + cnt;
    {
        int idx = b * 1024 + s * 256 + t;
        if (idx < N_NODES) row_ptr[idx] = shist[s * 256 + t];
    }
    if (blockIdx.x == 0 && t == 0) row_ptr[N_NODES] = N_EDGES;
    __syncthreads();   // all base reads done before cursors mutate

    // pass B: stage my window's records into LDS ordered by row
    for (int j = t; j < nrec; j += 256) {
        int2 rec = src[j];
        int  rl  = rec.x >> 18;
        if (rec.x != -1 && (rl >> 8) == s) {
            int lp = atomicAdd(&shist[rl], 1) - wstart;
            sstage[lp] = make_int2(rec.x & 0x3FFFF, rec.y);
        }
    }
    __syncthreads();
    // coalesced flush to contiguous region
    for (int j = t; j < wend - wstart; j += 256)
        edges[wstart + j] = sstage[j];
}

// ---------------- fused SpMM: quarter-wave (16 lanes) per row, ILP-8 ----------------
// Lane l owns dims [4l, 4l+4). MODE 0: cur_out = acc (fp16).
// MODE 1 (last layer): out = emb16[r] + cur1[r] + in16[r] + acc (fp32 store).
template <int MODE>
__global__ __launch_bounds__(256) void spmm_kernel(
    const int* __restrict__ row_ptr, const int2* __restrict__ edges,
    const __half* __restrict__ in16, const __half* __restrict__ emb16,
    const __half* __restrict__ cur1,
    float* __restrict__ out, __half* __restrict__ cur_out)
{
    int t = blockIdx.x * blockDim.x + threadIdx.x;
    int r = t >> 4;
    int l = t & 15;
    if (r >= N_NODES) return;
    int start = row_ptr[r];
    int end   = row_ptr[r + 1];
    int idx   = r * EMB + 4 * l;

    // prefetch epilogue terms (latency hides under the gather loop)
    union { int2 i; __half2 h[2]; } pe, p1, p2;
    if (MODE == 1) {
        pe.i = *(const int2*)(emb16 + idx);
        p1.i = *(const int2*)(cur1 + idx);
        p2.i = *(const int2*)(in16 + idx);
    }

    float ax = 0.f, ay = 0.f, az = 0.f, aw = 0.f;
    for (int j = start; j < end; j += 8) {
        int2 e[8];
#pragma unroll
        for (int k = 0; k < 8; ++k) e[k] = edges[j + k];   // pad-read past end ok
#pragma unroll
        for (int k = 0; k < 8; ++k) {
            bool ok = (j + k < end);
            int   c = ok ? e[k].x : 0;
            float v = ok ? __int_as_float(e[k].y) : 0.0f;
            union { int2 i; __half2 h[2]; } g;
            g.i = *(const int2*)(in16 + c * EMB + 4 * l);
            float2 x0 = __half22float2(g.h[0]);
            float2 x1 = __half22float2(g.h[1]);
            ax += v * x0.x; ay += v * x0.y;
            az += v * x1.x; aw += v * x1.y;
        }
    }

    if (MODE == 0) {
        union { int2 i; __half2 h[2]; } o;
        o.h[0] = __float22half2_rn(make_float2(ax, ay));
        o.h[1] = __float22half2_rn(make_float2(az, aw));
        *(int2*)(cur_out + idx) = o.i;
    } else {
        float2 e0 = __half22float2(pe.h[0]), e1 = __half22float2(pe.h[1]);
        float2 c0 = __half22float2(p1.h[0]), c1 = __half22float2(p1.h[1]);
        float2 d0 = __half22float2(p2.h[0]), d1 = __half22float2(p2.h[1]);
        float4 o = make_float4(e0.x + c0.x + d0.x + ax,
                               e0.y + c0.y + d0.y + ay,
                               e1.x + c1.x + d1.x + az,
                               e1.y + c1.y + d1.y + aw);
        *(float4*)(out + idx) = o;
    }
}

extern "C" void kernel_launch(void* const* d_in, const int* in_sizes, int n_in,
                              void* d_out, int out_size, void* d_ws, size_t ws_size,
                              hipStream_t stream) {
    const float* user = (const float*)d_in[0];
    const float* item = (const float*)d_in[1];
    const int*   rows = (const int*)d_in[2];
    const int*   cols = (const int*)d_in[3];
    const float* vals = (const float*)d_in[4];
    float*       out  = (float*)d_out;

    // workspace layout (256B aligned), ~123 MB total
    char* p = (char*)d_ws;
    __half* emb16   = (__half*)p;  p += (size_t)N_ELEM * 2;             // 32 MB
    __half* cur1    = (__half*)p;  p += (size_t)N_ELEM * 2;             // 32 MB
    __half* cur2    = (__half*)p;  p += (size_t)N_ELEM * 2;             // 32 MB
    int2*   tmp     = (int2*)p;    p += (size_t)NBUCK * CAP * 8;        // 16.1 MB
    int2*   edges   = (int2*)p;    p += (size_t)(N_EDGES + 32) * 8;     // 9.6 MB + pad
    int*    row_ptr = (int*)p;     p += 1000448;                        // 250001*4 padded
    int*    bucket_cnt = (int*)p;  p += 1024;                           // memset
    int*    chunkcur   = (int*)p;  p += 1024;                           // memset

    hipMemsetAsync(bucket_cnt, 0, 2048, stream);   // bucket_cnt + chunkcur

    bin_init_kernel<<<NBLK1 + INIT_TILES, 256, 0, stream>>>(
        rows, cols, vals, chunkcur, bucket_cnt, tmp, user, item, emb16);
    place4_kernel<<<NBUCK * 4, 256, 0, stream>>>(
        chunkcur, bucket_cnt, tmp, row_ptr, edges);

    const int spmm_blocks = (N_NODES * 16 + 255) / 256;   // 15625
    spmm_kernel<0><<<spmm_blocks, 256, 0, stream>>>(row_ptr, edges, emb16, emb16, cur1, out, cur1);
    spmm_kernel<0><<<spmm_blocks, 256, 0, stream>>>(row_ptr, edges, cur1, emb16, cur1, out, cur2);
    spmm_kernel<1><<<spmm_blocks, 256, 0, stream>>>(row_ptr, edges, cur2, emb16, cur1, out, nullptr);
}